// Round 1
// baseline (505.540 us; speedup 1.0000x reference)
//
#include <hip/hip_runtime.h>

#define DIM 2048
#define NB 11
#define ROWS_PER_BLOCK 32
#define TPB 256

// ws layout: per j, 16 floats: slots [0..10] = chain scales in application
// order (s0 first), slot [11] = source index into x's last dim (int bits).
__global__ void monarch_prep(const float* __restrict__ blocks,
                             const int* __restrict__ perms,
                             float* __restrict__ ws) {
    int j = blockIdx.x * blockDim.x + threadIdx.x;
    if (j >= DIM) return;
    int k = j;
    float sc[NB];
    sc[NB - 1] = blocks[(NB - 1) * DIM + k];
    for (int i = NB - 2; i >= 0; --i) {
        k = perms[i * DIM + k];
        sc[i] = blocks[i * DIM + k];
    }
    float* o = ws + (size_t)j * 16;
    #pragma unroll
    for (int i = 0; i < NB; ++i) o[i] = sc[i];
    ((int*)o)[NB] = k;  // src index
}

__global__ __launch_bounds__(TPB) void monarch_apply(const float* __restrict__ x,
                                                     const float* __restrict__ ws,
                                                     float* __restrict__ out,
                                                     int nrows) {
    // Each block: 256 threads x 4 consecutive j = 1024 j's, so 2 j-groups
    // cover DIM=2048; blockIdx.x>>1 selects the row slab.
    const int jg = blockIdx.x & 1;
    const int rowblk = blockIdx.x >> 1;
    const int j0 = jg * 1024 + threadIdx.x * 4;

    // Load the per-j multiply chains into registers (fully unrolled -> VGPRs).
    float sc[NB][4];
    int src[4];
    #pragma unroll
    for (int q = 0; q < 4; ++q) {
        const float* w = ws + (size_t)(j0 + q) * 16;
        #pragma unroll
        for (int i = 0; i < NB; ++i) sc[i][q] = w[i];
        src[q] = ((const int*)w)[NB];
    }
    const bool consec = (src[1] == src[0] + 1) && (src[2] == src[0] + 2) &&
                        (src[3] == src[0] + 3) && ((src[0] & 3) == 0);

    const int r0 = rowblk * ROWS_PER_BLOCK;
    for (int r = 0; r < ROWS_PER_BLOCK; ++r) {
        const int row_i = r0 + r;
        if (row_i >= nrows) return;
        const size_t row = (size_t)row_i;
        const float* xr = x + row * DIM;
        float4 v;
        if (consec) {
            v = *(const float4*)(xr + src[0]);   // 16B coalesced load
        } else {
            v.x = xr[src[0]]; v.y = xr[src[1]];
            v.z = xr[src[2]]; v.w = xr[src[3]];
        }
        // Sequential multiplies in the reference's exact order -> bit-exact
        // fp32 rounding (no reassociation without fast-math).
        #pragma unroll
        for (int i = 0; i < NB; ++i) {
            v.x *= sc[i][0];
            v.y *= sc[i][1];
            v.z *= sc[i][2];
            v.w *= sc[i][3];
        }
        *(float4*)(out + row * DIM + j0) = v;    // 16B coalesced store
    }
}

extern "C" void kernel_launch(void* const* d_in, const int* in_sizes, int n_in,
                              void* d_out, int out_size, void* d_ws, size_t ws_size,
                              hipStream_t stream) {
    const float* x      = (const float*)d_in[0];
    const float* blocks = (const float*)d_in[1];
    const int*   perms  = (const int*)d_in[2];
    float* out = (float*)d_out;
    float* ws  = (float*)d_ws;

    // Kernel 1: build per-j {11 chain scales, src index} (ws re-poisoned
    // before every call, so this must run every launch; it's negligible).
    monarch_prep<<<(DIM + TPB - 1) / TPB, TPB, 0, stream>>>(blocks, perms, ws);

    const int nrows = in_sizes[0] / DIM;  // 4*8192 = 32768
    const int grid = 2 * ((nrows + ROWS_PER_BLOCK - 1) / ROWS_PER_BLOCK);
    monarch_apply<<<grid, TPB, 0, stream>>>(x, ws, out, nrows);
}